// Round 8
// baseline (379.018 us; speedup 1.0000x reference)
//
#include <hip/hip_runtime.h>
#include <math.h>

#define Bd 2
#define Nd 2048
#define Cd 256
#define Ld 4
#define Hd 8
#define Md (Bd*Nd)      // 4096
#define BHd 16
#define U32d 1024       // (B*H)*(N/32) units of 32 q-rows
#define SPLITd 4

typedef __attribute__((ext_vector_type(8))) short bf16x8;
typedef __attribute__((ext_vector_type(4))) float f32x4;
typedef __attribute__((ext_vector_type(16))) float f32x16;
typedef __attribute__((ext_vector_type(4))) short shortx4;

static __device__ inline f32x4 mfma16(bf16x8 a, bf16x8 b, f32x4 c) {
    return __builtin_amdgcn_mfma_f32_16x16x32_bf16(a, b, c, 0, 0, 0);
}
static __device__ inline f32x16 mfma32(bf16x8 a, bf16x8 b, f32x16 c) {
    return __builtin_amdgcn_mfma_f32_32x32x16_bf16(a, b, c, 0, 0, 0);
}
static __device__ inline short f2bf(float f) {
    union { float f; unsigned u; } v; v.f = f;
    unsigned r = (v.u + 0x7fff + ((v.u >> 16) & 1)) >> 16;
    return (short)r;
}
static __device__ inline unsigned pkbf(float a, float b) {
    unsigned r;
    asm("v_cvt_pk_bf16_f32 %0, %1, %2" : "=v"(r) : "v"(a), "v"(b));
    return r;
}
static __device__ inline float bf2f(unsigned u) {
    return __uint_as_float((u & 0xffffu) << 16);
}

// ------------------------------------------------ fused prep:
// blocks [0,1536): weight transposes; [1536, 1536+4096): pos-embed add
__global__ __launch_bounds__(256)
void prep_kernel(const float* __restrict__ x_in, const float* __restrict__ qkv_w,
                 const float* __restrict__ proj_w, const float* __restrict__ w1,
                 const float* __restrict__ w2, float* __restrict__ xf,
                 short* __restrict__ xb, short* __restrict__ qkvT,
                 short* __restrict__ projT, short* __restrict__ w1T,
                 short* __restrict__ w2T, float qscale)
{
    __shared__ float tile[32][33];
    int id = blockIdx.x;
    if (id < 1536) {
        const float* src; short* dst; int Nc; float scale; int lim; int rem; int l;
        if (id < 768)       { l = id / 192;         rem = id % 192; src = qkv_w;  dst = qkvT;  Nc = 768; scale = qscale; lim = 256; }
        else if (id < 1024) { l = (id - 768) / 64;  rem = (id - 768) % 64;  src = proj_w; dst = projT; Nc = 256; scale = 1.f; lim = 0; }
        else if (id < 1280) { l = (id - 1024) / 64; rem = (id - 1024) % 64; src = w1;     dst = w1T;   Nc = 256; scale = 1.f; lim = 0; }
        else                { l = (id - 1280) / 64; rem = (id - 1280) % 64; src = w2;     dst = w2T;   Nc = 256; scale = 1.f; lim = 0; }
        int nb = Nc >> 5;
        int c0 = (rem % nb) * 32, k0 = (rem / nb) * 32;
        src += (size_t)l * 256 * Nc;
        dst += (size_t)l * Nc * 256;
        int tx = threadIdx.x & 31, ty = threadIdx.x >> 5;
#pragma unroll
        for (int i = 0; i < 4; i++) {
            int k = ty + 8 * i;
            tile[k][tx] = src[(size_t)(k0 + k) * Nc + c0 + tx];
        }
        __syncthreads();
#pragma unroll
        for (int i = 0; i < 4; i++) {
            int cc = ty + 8 * i;
            int col = c0 + cc;
            float v = tile[tx][cc];
            if (col < lim) v *= scale;
            dst[(size_t)col * 256 + k0 + tx] = f2bf(v);
        }
    } else {
        int i = (id - 1536) * 256 + threadIdx.x;
        int c = i & (Cd - 1);
        int n = (i >> 8) & (Nd - 1);
        const float kneg = -9.210340371976184f / 256.0f;
        float div = __expf((float)(c & ~1) * kneg);
        float ang = (float)n * div;
        float pe = (c & 1) ? cosf(ang) : sinf(ang);
        float v = x_in[i] + pe;
        xf[i] = v;
        xb[i] = f2bf(v);
    }
}

// ------------------------------------------------ QKV GEMM (bf16, no LDS)
__global__ __launch_bounds__(256)
void qkv_gemm_kernel(const short* __restrict__ Ab, const short* __restrict__ WT,
                     short* __restrict__ Qb, short* __restrict__ Kb,
                     short* __restrict__ Vtb)
{
    int t = threadIdx.x, w = t >> 6, l = t & 63, c = l & 15, g = l >> 4;
    int rowBase = blockIdx.y * 128 + w * 32;
    int colBase = blockIdx.x * 32;
    const f32x4 zero = {0.f, 0.f, 0.f, 0.f};
    f32x4 acc[2][2] = {{zero, zero}, {zero, zero}};
    const short* ap0 = Ab + (size_t)(rowBase + c) * 256 + g * 8;
    const short* ap1 = ap0 + 16 * 256;
    const short* bp0 = WT + (size_t)(colBase + c) * 256 + g * 8;
    const short* bp1 = bp0 + 16 * 256;
#pragma unroll
    for (int kc = 0; kc < 256; kc += 32) {
        bf16x8 a0 = *(const bf16x8*)(ap0 + kc);
        bf16x8 a1 = *(const bf16x8*)(ap1 + kc);
        bf16x8 b0 = *(const bf16x8*)(bp0 + kc);
        bf16x8 b1 = *(const bf16x8*)(bp1 + kc);
        acc[0][0] = mfma16(a0, b0, acc[0][0]);
        acc[0][1] = mfma16(a0, b1, acc[0][1]);
        acc[1][0] = mfma16(a1, b0, acc[1][0]);
        acc[1][1] = mfma16(a1, b1, acc[1][1]);
    }
    int region = colBase >> 8;              // 0=Q 1=K 2=V (uniform per block)
    if (region < 2) {
        short* dst = (region == 0) ? Qb : Kb;
        int cb = colBase - region * 256;
#pragma unroll
        for (int m = 0; m < 2; m++)
#pragma unroll
            for (int n = 0; n < 2; n++)
#pragma unroll
                for (int r = 0; r < 4; r++)
                    dst[(size_t)(rowBase + 16 * m + 4 * g + r) * 256 + cb + 16 * n + c]
                        = f2bf(acc[m][n][r]);
    } else {
        int b = rowBase >> 11;
        int ntok0 = (rowBase & (Nd - 1)) + 4 * g;
#pragma unroll
        for (int m = 0; m < 2; m++)
#pragma unroll
            for (int n = 0; n < 2; n++) {
                int chg = colBase - 512 + 16 * n + c;        // h*32+chl
                shortx4 pkv;
#pragma unroll
                for (int r = 0; r < 4; r++) pkv[r] = f2bf(acc[m][n][r]);
                *(shortx4*)&Vtb[(size_t)((b * Hd + (chg >> 5)) * 32 + (chg & 31)) * Nd
                                + ntok0 + 16 * m] = pkv;
            }
    }
}

// ------------------------------------------------ attention partial
// 32x32 MFMA, fixed-max softmax (exp2 direct), permlane32 relayout,
// bf16-packed partials, register prefetch, XCD-aware swizzle.
// grid: 1024 1D. xcd=bid&7; group g=xcd*8+(bid>>7) -> (part,bh); qt from mid bits.
__global__ __launch_bounds__(256)
void attn_part_kernel(const short* __restrict__ Qb, const short* __restrict__ Kb,
                      const short* __restrict__ Vtb, unsigned* __restrict__ OPb,
                      float* __restrict__ Lsum)
{
    int t = threadIdx.x, w = t >> 6, l = t & 63;
    int l5 = l >> 5, q32 = l & 31;
    int bid = blockIdx.x;
    int xcd = bid & 7, j = bid >> 3;
    int grp = xcd * 8 + (j >> 4);          // 0..63: all 16 qt-blocks of a group on one XCD
    int qt = (j & 15) * 4 + w;
    int part = grp >> 4, bh = grp & 15;
    int b = bh >> 3, h = bh & 7;

    bf16x8 qf0, qf1;
    {
        const short* qp = Qb + ((size_t)(b * Nd + qt * 32 + q32)) * 256 + h * 32 + 8 * l5;
        qf0 = *(const bf16x8*)qp;
        qf1 = *(const bf16x8*)(qp + 16);
    }
    const int kstart = part * (Nd / SPLITd);
    const short* kb = Kb + (size_t)b * Nd * 256 + h * 32 + 8 * l5
                      + (size_t)(kstart + q32) * 256;
    const short* vb = Vtb + (size_t)(bh * 32 + q32) * Nd + 8 * l5 + kstart;

    f32x16 O;
#pragma unroll
    for (int i = 0; i < 16; i++) O[i] = 0.f;
    float lsum = 0.f;

    bf16x8 kf[2][2], vv[4];
#pragma unroll
    for (int sb = 0; sb < 2; sb++)
#pragma unroll
        for (int ks = 0; ks < 2; ks++)
            kf[sb][ks] = *(const bf16x8*)(kb + sb * 32 * 256 + ks * 16);
#pragma unroll
    for (int kc = 0; kc < 4; kc++)
        vv[kc] = *(const bf16x8*)(vb + 16 * kc);

    const int NT = (Nd / SPLITd) / 64;   // 8 tiles
    for (int it = 0; it < NT; ++it) {
        bool has_next = (it + 1) < NT;
        bf16x8 kfn[2][2], vvn[4];
        if (has_next) {
            const short* kn = kb + 64 * 256;
            const short* vn = vb + 64;
#pragma unroll
            for (int sb = 0; sb < 2; sb++)
#pragma unroll
                for (int ks = 0; ks < 2; ks++)
                    kfn[sb][ks] = *(const bf16x8*)(kn + sb * 32 * 256 + ks * 16);
#pragma unroll
            for (int kc = 0; kc < 4; kc++)
                vvn[kc] = *(const bf16x8*)(vn + 16 * kc);
        }

#pragma unroll
        for (int sb = 0; sb < 2; sb++) {
            f32x16 s;
#pragma unroll
            for (int i = 0; i < 16; i++) s[i] = 0.f;
            s = mfma32(kf[sb][0], qf0, s);
            s = mfma32(kf[sb][1], qf1, s);
            float e[16];
#pragma unroll
            for (int i = 0; i < 16; i++) e[i] = exp2f(s[i]);
            // tree sum (depth 4, not a 16-deep chain)
            float p0 = e[0] + e[1],  p1 = e[2] + e[3];
            float p2 = e[4] + e[5],  p3 = e[6] + e[7];
            float p4 = e[8] + e[9],  p5 = e[10] + e[11];
            float p6 = e[12] + e[13], p7 = e[14] + e[15];
            p0 += p1; p2 += p3; p4 += p5; p6 += p7;
            p0 += p2; p4 += p6;
            lsum += p0 + p4;                  // cross-half combine deferred
            unsigned wd[8];
#pragma unroll
            for (int i = 0; i < 8; i++) wd[i] = pkbf(e[2 * i], e[2 * i + 1]);
#pragma unroll
            for (int half = 0; half < 2; half++) {
                unsigned a0 = wd[4 * half], a1 = wd[4 * half + 1];
                unsigned b0 = wd[4 * half + 2], b1 = wd[4 * half + 3];
                asm("v_permlane32_swap_b32 %0, %1" : "+v"(a0), "+v"(b0));
                asm("v_permlane32_swap_b32 %0, %1" : "+v"(a1), "+v"(b1));
                union { unsigned u[4]; bf16x8 v; } pa;
                pa.u[0] = a0; pa.u[1] = a1; pa.u[2] = b0; pa.u[3] = b1;
                O = mfma32(pa.v, vv[2 * sb + half], O);
            }
        }
        kb += 64 * 256;
        vb += 64;
        if (has_next) {
#pragma unroll
            for (int sb = 0; sb < 2; sb++)
#pragma unroll
                for (int ks = 0; ks < 2; ks++) kf[sb][ks] = kfn[sb][ks];
#pragma unroll
            for (int kc = 0; kc < 4; kc++) vv[kc] = vvn[kc];
        }
    }

    lsum += __shfl_xor(lsum, 32, 64);

    int u = bh * 64 + qt;
    unsigned* opb = OPb + ((size_t)part * U32d + u) * 512;
#pragma unroll
    for (int i = 0; i < 16; i += 2) {
        int q = (i & 3) + 8 * (i >> 2) + 4 * l5;     // even row of the pair
        opb[(q >> 1) * 32 + q32] = pkbf(O[i], O[i + 1]);
    }
    if (l5 == 0) Lsum[((size_t)part * U32d + u) * 32 + q32] = lsum;
}

// ------------------------------------------------ proj GEMM fused with
// split-K combine + bias + residual + LN1. 512 thr / 8 waves / 16 rows.
__global__ __launch_bounds__(512)
void proj_ln_kernel(const unsigned* __restrict__ OPb, const float* __restrict__ Lsum,
                    const short* __restrict__ WT, const float* __restrict__ bias,
                    const float* __restrict__ resid, const float* __restrict__ gg,
                    const float* __restrict__ be, float* __restrict__ outf,
                    short* __restrict__ outb)
{
    __shared__ short Atile[16 * 264];
    __shared__ float red[8][16][2];
    int t = threadIdx.x;
    int rowBase = blockIdx.x * 16;

    // ---- combine: A[16][256] bf16 from OPb/Lsum
    {
        int r = t >> 5, seg = t & 31;
        int grow = rowBase + r;
        int bb = grow >> 11;
        int qt = (grow & (Nd - 1)) >> 5;
        int q = grow & 31;
        int h = seg >> 2;
        int dh0 = (seg & 3) * 8;
        int u = (bb * Hd + h) * 64 + qt;
        int sh = (q & 1) * 16;
        float o[8] = {0.f, 0.f, 0.f, 0.f, 0.f, 0.f, 0.f, 0.f};
        float L = 0.f;
#pragma unroll
        for (int p = 0; p < SPLITd; p++) {
            const unsigned* src = OPb + ((size_t)p * U32d + u) * 512 + (q >> 1) * 32 + dh0;
            uint4 w0 = *(const uint4*)src;
            uint4 w1 = *(const uint4*)(src + 4);
            o[0] += bf2f(w0.x >> sh); o[1] += bf2f(w0.y >> sh);
            o[2] += bf2f(w0.z >> sh); o[3] += bf2f(w0.w >> sh);
            o[4] += bf2f(w1.x >> sh); o[5] += bf2f(w1.y >> sh);
            o[6] += bf2f(w1.z >> sh); o[7] += bf2f(w1.w >> sh);
            L += Lsum[((size_t)p * U32d + u) * 32 + q];
        }
        float inv = 1.f / L;
        bf16x8 pk;
#pragma unroll
        for (int j = 0; j < 8; j++) pk[j] = f2bf(o[j] * inv);
        *(bf16x8*)&Atile[r * 264 + seg * 8] = pk;
    }
    __syncthreads();

    // ---- GEMM: wave w -> cols w*32 .. w*32+31
    int w = t >> 6, l = t & 63, c = l & 15, g = l >> 4;
    const f32x4 zero = {0.f, 0.f, 0.f, 0.f};
    f32x4 acc0 = zero, acc1 = zero;
    const short* bp0 = WT + (size_t)(w * 32 + c) * 256 + g * 8;
    const short* bp1 = bp0 + 16 * 256;
#pragma unroll
    for (int kc = 0; kc < 256; kc += 32) {
        bf16x8 a = *(const bf16x8*)&Atile[c * 264 + g * 8 + kc];
        acc0 = mfma16(a, *(const bf16x8*)(bp0 + kc), acc0);
        acc1 = mfma16(a, *(const bf16x8*)(bp1 + kc), acc1);
    }

    // ---- bias + residual, LN stats
    float vv[2][4], s_[4] = {0.f, 0.f, 0.f, 0.f}, sq_[4] = {0.f, 0.f, 0.f, 0.f};
    int col0 = w * 32 + c, col1 = col0 + 16;
    float bi0 = bias[col0], bi1 = bias[col1];
#pragma unroll
    for (int r = 0; r < 4; r++) {
        int row = rowBase + 4 * g + r;
        float v0 = acc0[r] + bi0 + resid[(size_t)row * 256 + col0];
        float v1 = acc1[r] + bi1 + resid[(size_t)row * 256 + col1];
        vv[0][r] = v0; vv[1][r] = v1;
        s_[r] += v0 + v1; sq_[r] += v0 * v0 + v1 * v1;
    }
#pragma unroll
    for (int off = 1; off <= 8; off <<= 1)
#pragma unroll
        for (int r = 0; r < 4; r++) {
            s_[r] += __shfl_xor(s_[r], off, 64);
            sq_[r] += __shfl_xor(sq_[r], off, 64);
        }
    if (c == 0)
#pragma unroll
        for (int r = 0; r < 4; r++) {
            red[w][4 * g + r][0] = s_[r];
            red[w][4 * g + r][1] = sq_[r];
        }
    __syncthreads();
    float mu[4], rs[4];
#pragma unroll
    for (int r = 0; r < 4; r++) {
        float S = 0.f, Q = 0.f;
#pragma unroll
        for (int ww = 0; ww < 8; ww++) { S += red[ww][4 * g + r][0]; Q += red[ww][4 * g + r][1]; }
        mu[r] = S * (1.f / 256.f);
        rs[r] = rsqrtf(Q * (1.f / 256.f) - mu[r] * mu[r] + 1e-6f);
    }
    float gv0 = gg[col0], bv0 = be[col0], gv1 = gg[col1], bv1 = be[col1];
#pragma unroll
    for (int r = 0; r < 4; r++) {
        int row = rowBase + 4 * g + r;
        float o0 = (vv[0][r] - mu[r]) * rs[r] * gv0 + bv0;
        float o1 = (vv[1][r] - mu[r]) * rs[r] * gv1 + bv1;
        outf[(size_t)row * 256 + col0] = o0;
        outf[(size_t)row * 256 + col1] = o1;
        outb[(size_t)row * 256 + col0] = f2bf(o0);
        outb[(size_t)row * 256 + col1] = f2bf(o1);
    }
}

// ------------------------------------------------ fused MLP:
// fc1+bias+GELU -> LDS -> fc2+bias + residual + LN2. 512 thr / 8 waves / 16 rows.
template<int LAST>
__global__ __launch_bounds__(512)
void mlp_kernel(const short* __restrict__ xbin, const short* __restrict__ W1T,
                const float* __restrict__ b1, const short* __restrict__ W2T,
                const float* __restrict__ b2, const float* __restrict__ resid,
                const float* __restrict__ gg, const float* __restrict__ be,
                float* __restrict__ outf, short* __restrict__ outb)
{
    __shared__ short A1[16 * 264];
    __shared__ short A2[16 * 264];
    __shared__ float red[8][16][2];
    int t = threadIdx.x;
    int rowBase = blockIdx.x * 16;

    {
        int r = t >> 5, seg = t & 31;
        *(bf16x8*)&A1[r * 264 + seg * 8] =
            *(const bf16x8*)(xbin + (size_t)(rowBase + r) * 256 + seg * 8);
    }
    __syncthreads();

    int w = t >> 6, l = t & 63, c = l & 15, g = l >> 4;
    const f32x4 zero = {0.f, 0.f, 0.f, 0.f};
    int col0 = w * 32 + c, col1 = col0 + 16;

    // ---- fc1 + GELU -> A2
    {
        f32x4 acc0 = zero, acc1 = zero;
        const short* bp0 = W1T + (size_t)(w * 32 + c) * 256 + g * 8;
        const short* bp1 = bp0 + 16 * 256;
#pragma unroll
        for (int kc = 0; kc < 256; kc += 32) {
            bf16x8 a = *(const bf16x8*)&A1[c * 264 + g * 8 + kc];
            acc0 = mfma16(a, *(const bf16x8*)(bp0 + kc), acc0);
            acc1 = mfma16(a, *(const bf16x8*)(bp1 + kc), acc1);
        }
        float bi0 = b1[col0], bi1 = b1[col1];
#pragma unroll
        for (int r = 0; r < 4; r++) {
            float v0 = acc0[r] + bi0, v1 = acc1[r] + bi1;
            v0 = 0.5f * v0 * (1.f + erff(v0 * 0.7071067811865476f));
            v1 = 0.5f * v1 * (1.f + erff(v1 * 0.7071067811865476f));
            A2[(4 * g + r) * 264 + col0] = f2bf(v0);
            A2[(4 * g + r) * 264 + col1] = f2bf(v1);
        }
    }
    __syncthreads();

    // ---- fc2 + bias + residual + LN2
    f32x4 acc0 = zero, acc1 = zero;
    const short* bp0 = W2T + (size_t)(w * 32 + c) * 256 + g * 8;
    const short* bp1 = bp0 + 16 * 256;
#pragma unroll
    for (int kc = 0; kc < 256; kc += 32) {
        bf16x8 a = *(const bf16x8*)&A2[c * 264 + g * 8 + kc];
        acc0 = mfma16(a, *(const bf16x8*)(bp0 + kc), acc0);
        acc1 = mfma16(a, *(const bf16x8*)(bp1 + kc), acc1);
    }
    float vv[2][4], s_[4] = {0.f, 0.f, 0.f, 0.f}, sq_[4] = {0.f, 0.f, 0.f, 0.f};
    float bi0 = b2[col0], bi1 = b2[col1];
#pragma unroll
    for (int r = 0; r < 4; r++) {
        int row = rowBase + 4 * g + r;
        float v0 = acc0[r] + bi0 + resid[(size_t)row * 256 + col0];
        float v1 = acc1[r] + bi1 + resid[(size_t)row * 256 + col1];
        vv[0][r] = v0; vv[1][r] = v1;
        s_[r] += v0 + v1; sq_[r] += v0 * v0 + v1 * v1;
    }
#pragma unroll
    for (int off = 1; off <= 8; off <<= 1)
#pragma unroll
        for (int r = 0; r < 4; r++) {
            s_[r] += __shfl_xor(s_[r], off, 64);
            sq_[r] += __shfl_xor(sq_[r], off, 64);
        }
    if (c == 0)
#pragma unroll
        for (int r = 0; r < 4; r++) {
            red[w][4 * g + r][0] = s_[r];
            red[w][4 * g + r][1] = sq_[r];
        }
    __syncthreads();
    float mu[4], rs[4];
#pragma unroll
    for (int r = 0; r < 4; r++) {
        float S = 0.f, Q = 0.f;
#pragma unroll
        for (int ww = 0; ww < 8; ww++) { S += red[ww][4 * g + r][0]; Q += red[ww][4 * g + r][1]; }
        mu[r] = S * (1.f / 256.f);
        rs[r] = rsqrtf(Q * (1.f / 256.f) - mu[r] * mu[r] + 1e-6f);
    }
    float gv0 = gg[col0], bv0 = be[col0], gv1 = gg[col1], bv1 = be[col1];
#pragma unroll
    for (int r = 0; r < 4; r++) {
        int row = rowBase + 4 * g + r;
        float o0 = (vv[0][r] - mu[r]) * rs[r] * gv0 + bv0;
        float o1 = (vv[1][r] - mu[r]) * rs[r] * gv1 + bv1;
        outf[(size_t)row * 256 + col0] = o0;
        outf[(size_t)row * 256 + col1] = o1;
        if (!LAST) {
            outb[(size_t)row * 256 + col0] = f2bf(o0);
            outb[(size_t)row * 256 + col1] = f2bf(o1);
        }
    }
}

// ------------------------------------------------ launch
extern "C" void kernel_launch(void* const* d_in, const int* in_sizes, int n_in,
                              void* d_out, int out_size, void* d_ws, size_t ws_size,
                              hipStream_t stream)
{
    const float* x_in   = (const float*)d_in[0];
    const float* qkv_w  = (const float*)d_in[1];
    const float* proj_w = (const float*)d_in[2];
    const float* proj_b = (const float*)d_in[3];
    const float* w1     = (const float*)d_in[4];
    const float* b1     = (const float*)d_in[5];
    const float* w2     = (const float*)d_in[6];
    const float* b2     = (const float*)d_in[7];
    const float* g1     = (const float*)d_in[8];
    const float* be1    = (const float*)d_in[9];
    const float* g2     = (const float*)d_in[10];
    const float* be2    = (const float*)d_in[11];
    float* outp = (float*)d_out;

    char* p = (char*)d_ws;
    float* xf    = (float*)p;    p += (size_t)Md * Cd * 4;
    short* xb    = (short*)p;    p += (size_t)Md * Cd * 2;
    short* Qb    = (short*)p;    p += (size_t)Md * Cd * 2;
    short* Kb    = (short*)p;    p += (size_t)Md * Cd * 2;
    short* Vtb   = (short*)p;    p += (size_t)Md * Cd * 2;
    unsigned* OPb = (unsigned*)p; p += (size_t)SPLITd * U32d * 512 * 4;
    float* Lsum  = (float*)p;    p += (size_t)SPLITd * U32d * 32 * 4;
    short* qkvT  = (short*)p;    p += (size_t)Ld * 768 * 256 * 2;
    short* projT = (short*)p;    p += (size_t)Ld * 256 * 256 * 2;
    short* w1T   = (short*)p;    p += (size_t)Ld * 256 * 256 * 2;
    short* w2T   = (short*)p;    p += (size_t)Ld * 256 * 256 * 2;

    const float QSCALE = 0.17677669529663687f * 1.4426950408889634f; // 1/sqrt(32)*log2e
    prep_kernel<<<1536 + Md * Cd / 256, 256, 0, stream>>>(
        x_in, qkv_w, proj_w, w1, w2, xf, xb, qkvT, projT, w1T, w2T, QSCALE);

    for (int l = 0; l < Ld; l++) {
        qkv_gemm_kernel<<<dim3(24, 32), 256, 0, stream>>>(
            xb, qkvT + (size_t)l * 768 * 256, Qb, Kb, Vtb);
        attn_part_kernel<<<1024, 256, 0, stream>>>(Qb, Kb, Vtb, OPb, Lsum);
        proj_ln_kernel<<<Md / 16, 512, 0, stream>>>(
            OPb, Lsum, projT + (size_t)l * 65536, proj_b + l * 256, xf,
            g1 + l * 256, be1 + l * 256, xf, xb);
        if (l == Ld - 1)
            mlp_kernel<1><<<Md / 16, 512, 0, stream>>>(
                xb, w1T + (size_t)l * 65536, b1 + l * 256,
                w2T + (size_t)l * 65536, b2 + l * 256, xf,
                g2 + l * 256, be2 + l * 256, outp, nullptr);
        else
            mlp_kernel<0><<<Md / 16, 512, 0, stream>>>(
                xb, w1T + (size_t)l * 65536, b1 + l * 256,
                w2T + (size_t)l * 65536, b2 + l * 256, xf,
                g2 + l * 256, be2 + l * 256, xf, xb);
    }
}

// Round 9
// 323.191 us; speedup vs baseline: 1.1727x; 1.1727x over previous
//
#include <hip/hip_runtime.h>
#include <math.h>

#define Bd 2
#define Nd 2048
#define Cd 256
#define Ld 4
#define Hd 8
#define Md (Bd*Nd)      // 4096
#define BHd 16
#define U32d 1024       // (B*H)*(N/32) units of 32 q-rows
#define SPLITd 4

typedef __attribute__((ext_vector_type(8))) short bf16x8;
typedef __attribute__((ext_vector_type(4))) float f32x4;
typedef __attribute__((ext_vector_type(16))) float f32x16;
typedef __attribute__((ext_vector_type(4))) short shortx4;

static __device__ inline f32x4 mfma16(bf16x8 a, bf16x8 b, f32x4 c) {
    return __builtin_amdgcn_mfma_f32_16x16x32_bf16(a, b, c, 0, 0, 0);
}
static __device__ inline f32x16 mfma32(bf16x8 a, bf16x8 b, f32x16 c) {
    return __builtin_amdgcn_mfma_f32_32x32x16_bf16(a, b, c, 0, 0, 0);
}
static __device__ inline short f2bf(float f) {
    union { float f; unsigned u; } v; v.f = f;
    unsigned r = (v.u + 0x7fff + ((v.u >> 16) & 1)) >> 16;
    return (short)r;
}
static __device__ inline unsigned pkbf(float a, float b) {
    unsigned r;
    asm("v_cvt_pk_bf16_f32 %0, %1, %2" : "=v"(r) : "v"(a), "v"(b));
    return r;
}
static __device__ inline float bf2f(unsigned u) {
    return __uint_as_float((u & 0xffffu) << 16);
}

// ------------------------------------------------ fused prep:
// blocks [0,1536): weight transposes; [1536, 1536+4096): pos-embed add
__global__ __launch_bounds__(256)
void prep_kernel(const float* __restrict__ x_in, const float* __restrict__ qkv_w,
                 const float* __restrict__ proj_w, const float* __restrict__ w1,
                 const float* __restrict__ w2, float* __restrict__ xf,
                 short* __restrict__ xb, short* __restrict__ qkvT,
                 short* __restrict__ projT, short* __restrict__ w1T,
                 short* __restrict__ w2T, float qscale)
{
    __shared__ float tile[32][33];
    int id = blockIdx.x;
    if (id < 1536) {
        const float* src; short* dst; int Nc; float scale; int lim; int rem; int l;
        if (id < 768)       { l = id / 192;         rem = id % 192; src = qkv_w;  dst = qkvT;  Nc = 768; scale = qscale; lim = 256; }
        else if (id < 1024) { l = (id - 768) / 64;  rem = (id - 768) % 64;  src = proj_w; dst = projT; Nc = 256; scale = 1.f; lim = 0; }
        else if (id < 1280) { l = (id - 1024) / 64; rem = (id - 1024) % 64; src = w1;     dst = w1T;   Nc = 256; scale = 1.f; lim = 0; }
        else                { l = (id - 1280) / 64; rem = (id - 1280) % 64; src = w2;     dst = w2T;   Nc = 256; scale = 1.f; lim = 0; }
        int nb = Nc >> 5;
        int c0 = (rem % nb) * 32, k0 = (rem / nb) * 32;
        src += (size_t)l * 256 * Nc;
        dst += (size_t)l * Nc * 256;
        int tx = threadIdx.x & 31, ty = threadIdx.x >> 5;
#pragma unroll
        for (int i = 0; i < 4; i++) {
            int k = ty + 8 * i;
            tile[k][tx] = src[(size_t)(k0 + k) * Nc + c0 + tx];
        }
        __syncthreads();
#pragma unroll
        for (int i = 0; i < 4; i++) {
            int cc = ty + 8 * i;
            int col = c0 + cc;
            float v = tile[tx][cc];
            if (col < lim) v *= scale;
            dst[(size_t)col * 256 + k0 + tx] = f2bf(v);
        }
    } else {
        int i = (id - 1536) * 256 + threadIdx.x;
        int c = i & (Cd - 1);
        int n = (i >> 8) & (Nd - 1);
        const float kneg = -9.210340371976184f / 256.0f;
        float div = __expf((float)(c & ~1) * kneg);
        float ang = (float)n * div;
        float pe = (c & 1) ? cosf(ang) : sinf(ang);
        float v = x_in[i] + pe;
        xf[i] = v;
        xb[i] = f2bf(v);
    }
}

// ------------------------------------------------ QKV GEMM (bf16, no LDS)
// Q,K out: per-head [bh][n][32]; V out: [bh][32][n]
__global__ __launch_bounds__(256)
void qkv_gemm_kernel(const short* __restrict__ Ab, const short* __restrict__ WT,
                     short* __restrict__ Qh, short* __restrict__ Kh,
                     short* __restrict__ Vtb)
{
    int t = threadIdx.x, w = t >> 6, l = t & 63, c = l & 15, g = l >> 4;
    int rowBase = blockIdx.y * 128 + w * 32;
    int colBase = blockIdx.x * 32;
    const f32x4 zero = {0.f, 0.f, 0.f, 0.f};
    f32x4 acc[2][2] = {{zero, zero}, {zero, zero}};
    const short* ap0 = Ab + (size_t)(rowBase + c) * 256 + g * 8;
    const short* ap1 = ap0 + 16 * 256;
    const short* bp0 = WT + (size_t)(colBase + c) * 256 + g * 8;
    const short* bp1 = bp0 + 16 * 256;
#pragma unroll
    for (int kc = 0; kc < 256; kc += 32) {
        bf16x8 a0 = *(const bf16x8*)(ap0 + kc);
        bf16x8 a1 = *(const bf16x8*)(ap1 + kc);
        bf16x8 b0 = *(const bf16x8*)(bp0 + kc);
        bf16x8 b1 = *(const bf16x8*)(bp1 + kc);
        acc[0][0] = mfma16(a0, b0, acc[0][0]);
        acc[0][1] = mfma16(a0, b1, acc[0][1]);
        acc[1][0] = mfma16(a1, b0, acc[1][0]);
        acc[1][1] = mfma16(a1, b1, acc[1][1]);
    }
    int region = colBase >> 8;              // 0=Q 1=K 2=V (uniform per block)
    if (region < 2) {
        short* dst = (region == 0) ? Qh : Kh;
        int cb = colBase - region * 256;
#pragma unroll
        for (int m = 0; m < 2; m++)
#pragma unroll
            for (int n = 0; n < 2; n++) {
                int col = cb + 16 * n + c;
                int h = col >> 5, dh = col & 31;
#pragma unroll
                for (int r = 0; r < 4; r++) {
                    int tok = rowBase + 16 * m + 4 * g + r;
                    int b = tok >> 11, nt = tok & (Nd - 1);
                    dst[((size_t)(b * Hd + h) * Nd + nt) * 32 + dh] = f2bf(acc[m][n][r]);
                }
            }
    } else {
        int b = rowBase >> 11;
        int ntok0 = (rowBase & (Nd - 1)) + 4 * g;
#pragma unroll
        for (int m = 0; m < 2; m++)
#pragma unroll
            for (int n = 0; n < 2; n++) {
                int chg = colBase - 512 + 16 * n + c;        // h*32+chl
                shortx4 pkv;
#pragma unroll
                for (int r = 0; r < 4; r++) pkv[r] = f2bf(acc[m][n][r]);
                *(shortx4*)&Vtb[(size_t)((b * Hd + (chg >> 5)) * 32 + (chg & 31)) * Nd
                                + ntok0 + 16 * m] = pkv;
            }
    }
}

// ------------------------------------------------ attention partial
// 32x32 MFMA, fixed-max softmax, permlane32 relayout, bf16-packed partials,
// XCD swizzle, LDS-staged K/V (double-buffered, coalesced, 1 barrier/tile).
__global__ __launch_bounds__(256)
void attn_part_kernel(const short* __restrict__ Qh, const short* __restrict__ Kh,
                      const short* __restrict__ Vtb, unsigned* __restrict__ OPb,
                      float* __restrict__ Lsum)
{
    __shared__ short Ks[2][64 * 40];   // [key][dh] rows padded to 40 shorts (80B)
    __shared__ short Vs[2][32 * 72];   // [dh][key] rows padded to 72 shorts (144B)

    int t = threadIdx.x, w = t >> 6, l = t & 63;
    int l5 = l >> 5, q32 = l & 31;
    int bid = blockIdx.x;
    int xcd = bid & 7, j = bid >> 3;
    int grp = xcd * 8 + (j >> 4);          // all 16 qt-blocks of a group on one XCD
    int qt = (j & 15) * 4 + w;
    int part = grp >> 4, bh = grp & 15;

    // staging thread mapping
    int skey = t >> 2, sdh = (t & 3) * 8;   // K: 64 keys x 32 dh, 1 x bf16x8/thread
    int vrow = t >> 3, vcol = (t & 7) * 8;  // V: 32 dh  x 64 keys, 1 x bf16x8/thread

    const int kstart = part * (Nd / SPLITd);
    const short* kg = Kh + ((size_t)bh * Nd + kstart + skey) * 32 + sdh;
    const short* vg = Vtb + ((size_t)bh * 32 + vrow) * Nd + kstart + vcol;

    bf16x8 qf0, qf1;
    {
        const short* qp = Qh + ((size_t)bh * Nd + qt * 32 + q32) * 32 + 8 * l5;
        qf0 = *(const bf16x8*)qp;
        qf1 = *(const bf16x8*)(qp + 16);
    }

    f32x16 O;
#pragma unroll
    for (int i = 0; i < 16; i++) O[i] = 0.f;
    float lsum = 0.f;

    // prologue: stage tile 0 into buf 0
    {
        bf16x8 kr = *(const bf16x8*)kg;
        bf16x8 vr = *(const bf16x8*)vg;
        *(bf16x8*)&Ks[0][skey * 40 + sdh] = kr;
        *(bf16x8*)&Vs[0][vrow * 72 + vcol] = vr;
    }
    __syncthreads();

    const int NT = (Nd / SPLITd) / 64;   // 8 tiles
    int cur = 0;
    for (int it = 0; it < NT; ++it) {
        bool has_next = (it + 1) < NT;
        bf16x8 krn, vrn;
        if (has_next) {                     // issue next-tile global loads early
            kg += 64 * 32;
            vg += 64;
            krn = *(const bf16x8*)kg;
            vrn = *(const bf16x8*)vg;
        }

        // fragments from LDS
        bf16x8 kf[2][2], vv[4];
#pragma unroll
        for (int sb = 0; sb < 2; sb++)
#pragma unroll
            for (int ks = 0; ks < 2; ks++)
                kf[sb][ks] = *(const bf16x8*)&Ks[cur][(32 * sb + q32) * 40 + 8 * l5 + 16 * ks];
#pragma unroll
        for (int kc = 0; kc < 4; kc++)
            vv[kc] = *(const bf16x8*)&Vs[cur][q32 * 72 + 8 * l5 + 16 * kc];

#pragma unroll
        for (int sb = 0; sb < 2; sb++) {
            f32x16 s;
#pragma unroll
            for (int i = 0; i < 16; i++) s[i] = 0.f;
            s = mfma32(kf[sb][0], qf0, s);
            s = mfma32(kf[sb][1], qf1, s);
            float e[16];
#pragma unroll
            for (int i = 0; i < 16; i++) e[i] = exp2f(s[i]);
            float p0 = e[0] + e[1],  p1 = e[2] + e[3];
            float p2 = e[4] + e[5],  p3 = e[6] + e[7];
            float p4 = e[8] + e[9],  p5 = e[10] + e[11];
            float p6 = e[12] + e[13], p7 = e[14] + e[15];
            p0 += p1; p2 += p3; p4 += p5; p6 += p7;
            p0 += p2; p4 += p6;
            lsum += p0 + p4;
            unsigned wd[8];
#pragma unroll
            for (int i = 0; i < 8; i++) wd[i] = pkbf(e[2 * i], e[2 * i + 1]);
#pragma unroll
            for (int half = 0; half < 2; half++) {
                unsigned a0 = wd[4 * half], a1 = wd[4 * half + 1];
                unsigned b0 = wd[4 * half + 2], b1 = wd[4 * half + 3];
                asm("v_permlane32_swap_b32 %0, %1" : "+v"(a0), "+v"(b0));
                asm("v_permlane32_swap_b32 %0, %1" : "+v"(a1), "+v"(b1));
                union { unsigned u[4]; bf16x8 v; } pa;
                pa.u[0] = a0; pa.u[1] = a1; pa.u[2] = b0; pa.u[3] = b1;
                O = mfma32(pa.v, vv[2 * sb + half], O);
            }
        }

        if (has_next) {                     // write next tile, flip
            *(bf16x8*)&Ks[cur ^ 1][skey * 40 + sdh] = krn;
            *(bf16x8*)&Vs[cur ^ 1][vrow * 72 + vcol] = vrn;
            __syncthreads();
            cur ^= 1;
        }
    }

    lsum += __shfl_xor(lsum, 32, 64);

    int u = bh * 64 + qt;
    unsigned* opb = OPb + ((size_t)part * U32d + u) * 512;
#pragma unroll
    for (int i = 0; i < 16; i += 2) {
        int q = (i & 3) + 8 * (i >> 2) + 4 * l5;     // even row of the pair
        opb[(q >> 1) * 32 + q32] = pkbf(O[i], O[i + 1]);
    }
    if (l5 == 0) Lsum[((size_t)part * U32d + u) * 32 + q32] = lsum;
}

// ------------------------------------------------ proj GEMM fused with
// split-K combine + bias + residual + LN1. 512 thr / 8 waves / 16 rows.
__global__ __launch_bounds__(512)
void proj_ln_kernel(const unsigned* __restrict__ OPb, const float* __restrict__ Lsum,
                    const short* __restrict__ WT, const float* __restrict__ bias,
                    const float* __restrict__ resid, const float* __restrict__ gg,
                    const float* __restrict__ be, float* __restrict__ outf,
                    short* __restrict__ outb)
{
    __shared__ short Atile[16 * 264];
    __shared__ float red[8][16][2];
    int t = threadIdx.x;
    int rowBase = blockIdx.x * 16;

    // ---- combine: A[16][256] bf16 from OPb/Lsum
    {
        int r = t >> 5, seg = t & 31;
        int grow = rowBase + r;
        int bb = grow >> 11;
        int qt = (grow & (Nd - 1)) >> 5;
        int q = grow & 31;
        int h = seg >> 2;
        int dh0 = (seg & 3) * 8;
        int u = (bb * Hd + h) * 64 + qt;
        int sh = (q & 1) * 16;
        float o[8] = {0.f, 0.f, 0.f, 0.f, 0.f, 0.f, 0.f, 0.f};
        float L = 0.f;
#pragma unroll
        for (int p = 0; p < SPLITd; p++) {
            const unsigned* src = OPb + ((size_t)p * U32d + u) * 512 + (q >> 1) * 32 + dh0;
            uint4 w0 = *(const uint4*)src;
            uint4 w1 = *(const uint4*)(src + 4);
            o[0] += bf2f(w0.x >> sh); o[1] += bf2f(w0.y >> sh);
            o[2] += bf2f(w0.z >> sh); o[3] += bf2f(w0.w >> sh);
            o[4] += bf2f(w1.x >> sh); o[5] += bf2f(w1.y >> sh);
            o[6] += bf2f(w1.z >> sh); o[7] += bf2f(w1.w >> sh);
            L += Lsum[((size_t)p * U32d + u) * 32 + q];
        }
        float inv = 1.f / L;
        bf16x8 pk;
#pragma unroll
        for (int j = 0; j < 8; j++) pk[j] = f2bf(o[j] * inv);
        *(bf16x8*)&Atile[r * 264 + seg * 8] = pk;
    }
    __syncthreads();

    // ---- GEMM: wave w -> cols w*32 .. w*32+31
    int w = t >> 6, l = t & 63, c = l & 15, g = l >> 4;
    const f32x4 zero = {0.f, 0.f, 0.f, 0.f};
    f32x4 acc0 = zero, acc1 = zero;
    const short* bp0 = WT + (size_t)(w * 32 + c) * 256 + g * 8;
    const short* bp1 = bp0 + 16 * 256;
#pragma unroll
    for (int kc = 0; kc < 256; kc += 32) {
        bf16x8 a = *(const bf16x8*)&Atile[c * 264 + g * 8 + kc];
        acc0 = mfma16(a, *(const bf16x8*)(bp0 + kc), acc0);
        acc1 = mfma16(a, *(const bf16x8*)(bp1 + kc), acc1);
    }

    // ---- bias + residual, LN stats
    float vv[2][4], s_[4] = {0.f, 0.f, 0.f, 0.f}, sq_[4] = {0.f, 0.f, 0.f, 0.f};
    int col0 = w * 32 + c, col1 = col0 + 16;
    float bi0 = bias[col0], bi1 = bias[col1];
#pragma unroll
    for (int r = 0; r < 4; r++) {
        int row = rowBase + 4 * g + r;
        float v0 = acc0[r] + bi0 + resid[(size_t)row * 256 + col0];
        float v1 = acc1[r] + bi1 + resid[(size_t)row * 256 + col1];
        vv[0][r] = v0; vv[1][r] = v1;
        s_[r] += v0 + v1; sq_[r] += v0 * v0 + v1 * v1;
    }
#pragma unroll
    for (int off = 1; off <= 8; off <<= 1)
#pragma unroll
        for (int r = 0; r < 4; r++) {
            s_[r] += __shfl_xor(s_[r], off, 64);
            sq_[r] += __shfl_xor(sq_[r], off, 64);
        }
    if (c == 0)
#pragma unroll
        for (int r = 0; r < 4; r++) {
            red[w][4 * g + r][0] = s_[r];
            red[w][4 * g + r][1] = sq_[r];
        }
    __syncthreads();
    float mu[4], rs[4];
#pragma unroll
    for (int r = 0; r < 4; r++) {
        float S = 0.f, Q = 0.f;
#pragma unroll
        for (int ww = 0; ww < 8; ww++) { S += red[ww][4 * g + r][0]; Q += red[ww][4 * g + r][1]; }
        mu[r] = S * (1.f / 256.f);
        rs[r] = rsqrtf(Q * (1.f / 256.f) - mu[r] * mu[r] + 1e-6f);
    }
    float gv0 = gg[col0], bv0 = be[col0], gv1 = gg[col1], bv1 = be[col1];
#pragma unroll
    for (int r = 0; r < 4; r++) {
        int row = rowBase + 4 * g + r;
        float o0 = (vv[0][r] - mu[r]) * rs[r] * gv0 + bv0;
        float o1 = (vv[1][r] - mu[r]) * rs[r] * gv1 + bv1;
        outf[(size_t)row * 256 + col0] = o0;
        outf[(size_t)row * 256 + col1] = o1;
        outb[(size_t)row * 256 + col0] = f2bf(o0);
        outb[(size_t)row * 256 + col1] = f2bf(o1);
    }
}

// ------------------------------------------------ fused MLP:
// fc1+bias+GELU -> LDS -> fc2+bias + residual + LN2. 512 thr / 8 waves / 16 rows.
template<int LAST>
__global__ __launch_bounds__(512)
void mlp_kernel(const short* __restrict__ xbin, const short* __restrict__ W1T,
                const float* __restrict__ b1, const short* __restrict__ W2T,
                const float* __restrict__ b2, const float* __restrict__ resid,
                const float* __restrict__ gg, const float* __restrict__ be,
                float* __restrict__ outf, short* __restrict__ outb)
{
    __shared__ short A1[16 * 264];
    __shared__ short A2[16 * 264];
    __shared__ float red[8][16][2];
    int t = threadIdx.x;
    int rowBase = blockIdx.x * 16;

    {
        int r = t >> 5, seg = t & 31;
        *(bf16x8*)&A1[r * 264 + seg * 8] =
            *(const bf16x8*)(xbin + (size_t)(rowBase + r) * 256 + seg * 8);
    }
    __syncthreads();

    int w = t >> 6, l = t & 63, c = l & 15, g = l >> 4;
    const f32x4 zero = {0.f, 0.f, 0.f, 0.f};
    int col0 = w * 32 + c, col1 = col0 + 16;

    // ---- fc1 + GELU -> A2
    {
        f32x4 acc0 = zero, acc1 = zero;
        const short* bp0 = W1T + (size_t)(w * 32 + c) * 256 + g * 8;
        const short* bp1 = bp0 + 16 * 256;
#pragma unroll
        for (int kc = 0; kc < 256; kc += 32) {
            bf16x8 a = *(const bf16x8*)&A1[c * 264 + g * 8 + kc];
            acc0 = mfma16(a, *(const bf16x8*)(bp0 + kc), acc0);
            acc1 = mfma16(a, *(const bf16x8*)(bp1 + kc), acc1);
        }
        float bi0 = b1[col0], bi1 = b1[col1];
#pragma unroll
        for (int r = 0; r < 4; r++) {
            float v0 = acc0[r] + bi0, v1 = acc1[r] + bi1;
            v0 = 0.5f * v0 * (1.f + erff(v0 * 0.7071067811865476f));
            v1 = 0.5f * v1 * (1.f + erff(v1 * 0.7071067811865476f));
            A2[(4 * g + r) * 264 + col0] = f2bf(v0);
            A2[(4 * g + r) * 264 + col1] = f2bf(v1);
        }
    }
    __syncthreads();

    // ---- fc2 + bias + residual + LN2
    f32x4 acc0 = zero, acc1 = zero;
    const short* bp0 = W2T + (size_t)(w * 32 + c) * 256 + g * 8;
    const short* bp1 = bp0 + 16 * 256;
#pragma unroll
    for (int kc = 0; kc < 256; kc += 32) {
        bf16x8 a = *(const bf16x8*)&A2[c * 264 + g * 8 + kc];
        acc0 = mfma16(a, *(const bf16x8*)(bp0 + kc), acc0);
        acc1 = mfma16(a, *(const bf16x8*)(bp1 + kc), acc1);
    }
    float vv[2][4], s_[4] = {0.f, 0.f, 0.f, 0.f}, sq_[4] = {0.f, 0.f, 0.f, 0.f};
    float bi0 = b2[col0], bi1 = b2[col1];
#pragma unroll
    for (int r = 0; r < 4; r++) {
        int row = rowBase + 4 * g + r;
        float v0 = acc0[r] + bi0 + resid[(size_t)row * 256 + col0];
        float v1 = acc1[r] + bi1 + resid[(size_t)row * 256 + col1];
        vv[0][r] = v0; vv[1][r] = v1;
        s_[r] += v0 + v1; sq_[r] += v0 * v0 + v1 * v1;
    }
#pragma unroll
    for (int off = 1; off <= 8; off <<= 1)
#pragma unroll
        for (int r = 0; r < 4; r++) {
            s_[r] += __shfl_xor(s_[r], off, 64);
            sq_[r] += __shfl_xor(sq_[r], off, 64);
        }
    if (c == 0)
#pragma unroll
        for (int r = 0; r < 4; r++) {
            red[w][4 * g + r][0] = s_[r];
            red[w][4 * g + r][1] = sq_[r];
        }
    __syncthreads();
    float mu[4], rs[4];
#pragma unroll
    for (int r = 0; r < 4; r++) {
        float S = 0.f, Q = 0.f;
#pragma unroll
        for (int ww = 0; ww < 8; ww++) { S += red[ww][4 * g + r][0]; Q += red[ww][4 * g + r][1]; }
        mu[r] = S * (1.f / 256.f);
        rs[r] = rsqrtf(Q * (1.f / 256.f) - mu[r] * mu[r] + 1e-6f);
    }
    float gv0 = gg[col0], bv0 = be[col0], gv1 = gg[col1], bv1 = be[col1];
#pragma unroll
    for (int r = 0; r < 4; r++) {
        int row = rowBase + 4 * g + r;
        float o0 = (vv[0][r] - mu[r]) * rs[r] * gv0 + bv0;
        float o1 = (vv[1][r] - mu[r]) * rs[r] * gv1 + bv1;
        outf[(size_t)row * 256 + col0] = o0;
        outf[(size_t)row * 256 + col1] = o1;
        if (!LAST) {
            outb[(size_t)row * 256 + col0] = f2bf(o0);
            outb[(size_t)row * 256 + col1] = f2bf(o1);
        }
    }
}

// ------------------------------------------------ launch
extern "C" void kernel_launch(void* const* d_in, const int* in_sizes, int n_in,
                              void* d_out, int out_size, void* d_ws, size_t ws_size,
                              hipStream_t stream)
{
    const float* x_in   = (const float*)d_in[0];
    const float* qkv_w  = (const float*)d_in[1];
    const float* proj_w = (const float*)d_in[2];
    const float* proj_b = (const float*)d_in[3];
    const float* w1     = (const float*)d_in[4];
    const float* b1     = (const float*)d_in[5];
    const float* w2     = (const float*)d_in[6];
    const float* b2     = (const float*)d_in[7];
    const float* g1     = (const float*)d_in[8];
    const float* be1    = (const float*)d_in[9];
    const float* g2     = (const float*)d_in[10];
    const float* be2    = (const float*)d_in[11];
    float* outp = (float*)d_out;

    char* p = (char*)d_ws;
    float* xf    = (float*)p;    p += (size_t)Md * Cd * 4;
    short* xb    = (short*)p;    p += (size_t)Md * Cd * 2;
    short* Qh    = (short*)p;    p += (size_t)Md * Cd * 2;
    short* Kh    = (short*)p;    p += (size_t)Md * Cd * 2;
    short* Vtb   = (short*)p;    p += (size_t)Md * Cd * 2;
    unsigned* OPb = (unsigned*)p; p += (size_t)SPLITd * U32d * 512 * 4;
    float* Lsum  = (float*)p;    p += (size_t)SPLITd * U32d * 32 * 4;
    short* qkvT  = (short*)p;    p += (size_t)Ld * 768 * 256 * 2;
    short* projT = (short*)p;    p += (size_t)Ld * 256 * 256 * 2;
    short* w1T   = (short*)p;    p += (size_t)Ld * 256 * 256 * 2;
    short* w2T   = (short*)p;    p += (size_t)Ld * 256 * 256 * 2;

    const float QSCALE = 0.17677669529663687f * 1.4426950408889634f; // 1/sqrt(32)*log2e
    prep_kernel<<<1536 + Md * Cd / 256, 256, 0, stream>>>(
        x_in, qkv_w, proj_w, w1, w2, xf, xb, qkvT, projT, w1T, w2T, QSCALE);

    for (int l = 0; l < Ld; l++) {
        qkv_gemm_kernel<<<dim3(24, 32), 256, 0, stream>>>(
            xb, qkvT + (size_t)l * 768 * 256, Qh, Kh, Vtb);
        attn_part_kernel<<<1024, 256, 0, stream>>>(Qh, Kh, Vtb, OPb, Lsum);
        proj_ln_kernel<<<Md / 16, 512, 0, stream>>>(
            OPb, Lsum, projT + (size_t)l * 65536, proj_b + l * 256, xf,
            g1 + l * 256, be1 + l * 256, xf, xb);
        if (l == Ld - 1)
            mlp_kernel<1><<<Md / 16, 512, 0, stream>>>(
                xb, w1T + (size_t)l * 65536, b1 + l * 256,
                w2T + (size_t)l * 65536, b2 + l * 256, xf,
                g2 + l * 256, be2 + l * 256, outp, nullptr);
        else
            mlp_kernel<0><<<Md / 16, 512, 0, stream>>>(
                xb, w1T + (size_t)l * 65536, b1 + l * 256,
                w2T + (size_t)l * 65536, b2 + l * 256, xf,
                g2 + l * 256, be2 + l * 256, xf, xb);
    }
}

// Round 10
// 301.471 us; speedup vs baseline: 1.2572x; 1.0720x over previous
//
#include <hip/hip_runtime.h>
#include <math.h>

#define Bd 2
#define Nd 2048
#define Cd 256
#define Ld 4
#define Hd 8
#define Md (Bd*Nd)      // 4096
#define BHd 16
#define U32d 1024       // (B*H)*(N/32) units of 32 q-rows
#define SPLITd 4

typedef __attribute__((ext_vector_type(8))) short bf16x8;
typedef __attribute__((ext_vector_type(4))) float f32x4;
typedef __attribute__((ext_vector_type(16))) float f32x16;
typedef __attribute__((ext_vector_type(4))) short shortx4;

static __device__ inline f32x4 mfma16(bf16x8 a, bf16x8 b, f32x4 c) {
    return __builtin_amdgcn_mfma_f32_16x16x32_bf16(a, b, c, 0, 0, 0);
}
static __device__ inline f32x16 mfma32(bf16x8 a, bf16x8 b, f32x16 c) {
    return __builtin_amdgcn_mfma_f32_32x32x16_bf16(a, b, c, 0, 0, 0);
}
static __device__ inline short f2bf(float f) {
    union { float f; unsigned u; } v; v.f = f;
    unsigned r = (v.u + 0x7fff + ((v.u >> 16) & 1)) >> 16;
    return (short)r;
}
static __device__ inline unsigned pkbf(float a, float b) {
    unsigned r;
    asm("v_cvt_pk_bf16_f32 %0, %1, %2" : "=v"(r) : "v"(a), "v"(b));
    return r;
}
static __device__ inline float bf2f(unsigned u) {
    return __uint_as_float((u & 0xffffu) << 16);
}

// ------------------------------------------------ fused prep:
// blocks [0,1536): weight transposes; [1536, 1536+4096): pos-embed add
__global__ __launch_bounds__(256)
void prep_kernel(const float* __restrict__ x_in, const float* __restrict__ qkv_w,
                 const float* __restrict__ proj_w, const float* __restrict__ w1,
                 const float* __restrict__ w2, float* __restrict__ xf,
                 short* __restrict__ xb, short* __restrict__ qkvT,
                 short* __restrict__ projT, short* __restrict__ w1T,
                 short* __restrict__ w2T, float qscale)
{
    __shared__ float tile[32][33];
    int id = blockIdx.x;
    if (id < 1536) {
        const float* src; short* dst; int Nc; float scale; int lim; int rem; int l;
        if (id < 768)       { l = id / 192;         rem = id % 192; src = qkv_w;  dst = qkvT;  Nc = 768; scale = qscale; lim = 256; }
        else if (id < 1024) { l = (id - 768) / 64;  rem = (id - 768) % 64;  src = proj_w; dst = projT; Nc = 256; scale = 1.f; lim = 0; }
        else if (id < 1280) { l = (id - 1024) / 64; rem = (id - 1024) % 64; src = w1;     dst = w1T;   Nc = 256; scale = 1.f; lim = 0; }
        else                { l = (id - 1280) / 64; rem = (id - 1280) % 64; src = w2;     dst = w2T;   Nc = 256; scale = 1.f; lim = 0; }
        int nb = Nc >> 5;
        int c0 = (rem % nb) * 32, k0 = (rem / nb) * 32;
        src += (size_t)l * 256 * Nc;
        dst += (size_t)l * Nc * 256;
        int tx = threadIdx.x & 31, ty = threadIdx.x >> 5;
#pragma unroll
        for (int i = 0; i < 4; i++) {
            int k = ty + 8 * i;
            tile[k][tx] = src[(size_t)(k0 + k) * Nc + c0 + tx];
        }
        __syncthreads();
#pragma unroll
        for (int i = 0; i < 4; i++) {
            int cc = ty + 8 * i;
            int col = c0 + cc;
            float v = tile[tx][cc];
            if (col < lim) v *= scale;
            dst[(size_t)col * 256 + k0 + tx] = f2bf(v);
        }
    } else {
        int i = (id - 1536) * 256 + threadIdx.x;
        int c = i & (Cd - 1);
        int n = (i >> 8) & (Nd - 1);
        const float kneg = -9.210340371976184f / 256.0f;
        float div = __expf((float)(c & ~1) * kneg);
        float ang = (float)n * div;
        float pe = (c & 1) ? cosf(ang) : sinf(ang);
        float v = x_in[i] + pe;
        xf[i] = v;
        xb[i] = f2bf(v);
    }
}

// ------------------------------------------------ QKV GEMM (bf16, no LDS)
// Q,K out: per-head [bh][n][32]; V out: [bh][32][n]
__global__ __launch_bounds__(256)
void qkv_gemm_kernel(const short* __restrict__ Ab, const short* __restrict__ WT,
                     short* __restrict__ Qh, short* __restrict__ Kh,
                     short* __restrict__ Vtb)
{
    int t = threadIdx.x, w = t >> 6, l = t & 63, c = l & 15, g = l >> 4;
    int rowBase = blockIdx.y * 128 + w * 32;
    int colBase = blockIdx.x * 32;
    const f32x4 zero = {0.f, 0.f, 0.f, 0.f};
    f32x4 acc[2][2] = {{zero, zero}, {zero, zero}};
    const short* ap0 = Ab + (size_t)(rowBase + c) * 256 + g * 8;
    const short* ap1 = ap0 + 16 * 256;
    const short* bp0 = WT + (size_t)(colBase + c) * 256 + g * 8;
    const short* bp1 = bp0 + 16 * 256;
#pragma unroll
    for (int kc = 0; kc < 256; kc += 32) {
        bf16x8 a0 = *(const bf16x8*)(ap0 + kc);
        bf16x8 a1 = *(const bf16x8*)(ap1 + kc);
        bf16x8 b0 = *(const bf16x8*)(bp0 + kc);
        bf16x8 b1 = *(const bf16x8*)(bp1 + kc);
        acc[0][0] = mfma16(a0, b0, acc[0][0]);
        acc[0][1] = mfma16(a0, b1, acc[0][1]);
        acc[1][0] = mfma16(a1, b0, acc[1][0]);
        acc[1][1] = mfma16(a1, b1, acc[1][1]);
    }
    int region = colBase >> 8;              // 0=Q 1=K 2=V (uniform per block)
    if (region < 2) {
        short* dst = (region == 0) ? Qh : Kh;
        int cb = colBase - region * 256;
#pragma unroll
        for (int m = 0; m < 2; m++)
#pragma unroll
            for (int n = 0; n < 2; n++) {
                int col = cb + 16 * n + c;
                int h = col >> 5, dh = col & 31;
#pragma unroll
                for (int r = 0; r < 4; r++) {
                    int tok = rowBase + 16 * m + 4 * g + r;
                    int b = tok >> 11, nt = tok & (Nd - 1);
                    dst[((size_t)(b * Hd + h) * Nd + nt) * 32 + dh] = f2bf(acc[m][n][r]);
                }
            }
    } else {
        int b = rowBase >> 11;
        int ntok0 = (rowBase & (Nd - 1)) + 4 * g;
#pragma unroll
        for (int m = 0; m < 2; m++)
#pragma unroll
            for (int n = 0; n < 2; n++) {
                int chg = colBase - 512 + 16 * n + c;        // h*32+chl
                shortx4 pkv;
#pragma unroll
                for (int r = 0; r < 4; r++) pkv[r] = f2bf(acc[m][n][r]);
                *(shortx4*)&Vtb[(size_t)((b * Hd + (chg >> 5)) * 32 + (chg & 31)) * Nd
                                + ntok0 + 16 * m] = pkv;
            }
    }
}

// ------------------------------------------------ attention partial
// 8 waves/block (8 qt), LDS-staged K/V double-buffered, XCD swizzle,
// fixed-max softmax, permlane32 relayout, bf16-packed partials.
__global__ __launch_bounds__(512)
void attn_part_kernel(const short* __restrict__ Qh, const short* __restrict__ Kh,
                      const short* __restrict__ Vtb, unsigned* __restrict__ OPb,
                      float* __restrict__ Lsum)
{
    __shared__ short Ks[2][64 * 40];   // [key][dh] rows padded to 40 shorts
    __shared__ short Vs[2][32 * 72];   // [dh][key] rows padded to 72 shorts

    int t = threadIdx.x, w = t >> 6, l = t & 63;
    int l5 = l >> 5, q32 = l & 31;
    int bid = blockIdx.x;
    int xcd = bid & 7, j = bid >> 3;       // j in [0,64)
    int grp = xcd * 8 + (j >> 3);          // 8 blocks of a group share an XCD
    int qt = (j & 7) * 8 + w;              // 0..63
    int part = grp >> 4, bh = grp & 15;

    // staging: waves 0-3 stage K, waves 4-7 stage V (wave-uniform branch)
    bool isK = (t < 256);
    int t2 = t & 255;
    int koff = (t2 >> 2) * 40 + (t2 & 3) * 8;       // K: key=t2>>2, dh=(t2&3)*8
    int voff = (t2 >> 3) * 72 + (t2 & 7) * 8;       // V: dh=t2>>3, key=(t2&7)*8
    int soff = isK ? koff : voff;
    long sstep = isK ? 64 * 32 : 64;

    const int kstart = part * (Nd / SPLITd);
    const short* sg = isK
        ? Kh + ((size_t)bh * Nd + kstart + (t2 >> 2)) * 32 + (t2 & 3) * 8
        : Vtb + ((size_t)bh * 32 + (t2 >> 3)) * Nd + kstart + (t2 & 7) * 8;

    bf16x8 qf0, qf1;
    {
        const short* qp = Qh + ((size_t)bh * Nd + qt * 32 + q32) * 32 + 8 * l5;
        qf0 = *(const bf16x8*)qp;
        qf1 = *(const bf16x8*)(qp + 16);
    }

    f32x16 O;
#pragma unroll
    for (int i = 0; i < 16; i++) O[i] = 0.f;
    float lsum = 0.f;

    // prologue: stage tile 0 into buf 0
    {
        bf16x8 r0 = *(const bf16x8*)sg;
        *(bf16x8*)((isK ? Ks[0] : Vs[0]) + soff) = r0;
    }
    __syncthreads();

    const int NT = (Nd / SPLITd) / 64;   // 8 tiles
    int cur = 0;
    for (int it = 0; it < NT; ++it) {
        bool has_next = (it + 1) < NT;
        bf16x8 nxt;
        if (has_next) {                     // issue next-tile global load early
            sg += sstep;
            nxt = *(const bf16x8*)sg;
        }

        bf16x8 kf[2][2], vv[4];
#pragma unroll
        for (int sb = 0; sb < 2; sb++)
#pragma unroll
            for (int ks = 0; ks < 2; ks++)
                kf[sb][ks] = *(const bf16x8*)&Ks[cur][(32 * sb + q32) * 40 + 8 * l5 + 16 * ks];
#pragma unroll
        for (int kc = 0; kc < 4; kc++)
            vv[kc] = *(const bf16x8*)&Vs[cur][q32 * 72 + 8 * l5 + 16 * kc];

#pragma unroll
        for (int sb = 0; sb < 2; sb++) {
            f32x16 s;
#pragma unroll
            for (int i = 0; i < 16; i++) s[i] = 0.f;
            s = mfma32(kf[sb][0], qf0, s);
            s = mfma32(kf[sb][1], qf1, s);
            float e[16];
#pragma unroll
            for (int i = 0; i < 16; i++) e[i] = exp2f(s[i]);
            float p0 = e[0] + e[1],  p1 = e[2] + e[3];
            float p2 = e[4] + e[5],  p3 = e[6] + e[7];
            float p4 = e[8] + e[9],  p5 = e[10] + e[11];
            float p6 = e[12] + e[13], p7 = e[14] + e[15];
            p0 += p1; p2 += p3; p4 += p5; p6 += p7;
            p0 += p2; p4 += p6;
            lsum += p0 + p4;
            unsigned wd[8];
#pragma unroll
            for (int i = 0; i < 8; i++) wd[i] = pkbf(e[2 * i], e[2 * i + 1]);
#pragma unroll
            for (int half = 0; half < 2; half++) {
                unsigned a0 = wd[4 * half], a1 = wd[4 * half + 1];
                unsigned b0 = wd[4 * half + 2], b1 = wd[4 * half + 3];
                asm("v_permlane32_swap_b32 %0, %1" : "+v"(a0), "+v"(b0));
                asm("v_permlane32_swap_b32 %0, %1" : "+v"(a1), "+v"(b1));
                union { unsigned u[4]; bf16x8 v; } pa;
                pa.u[0] = a0; pa.u[1] = a1; pa.u[2] = b0; pa.u[3] = b1;
                O = mfma32(pa.v, vv[2 * sb + half], O);
            }
        }

        if (has_next) {                     // write next tile, flip
            *(bf16x8*)((isK ? Ks[cur ^ 1] : Vs[cur ^ 1]) + soff) = nxt;
            __syncthreads();
            cur ^= 1;
        }
    }

    lsum += __shfl_xor(lsum, 32, 64);

    int u = bh * 64 + qt;
    unsigned* opb = OPb + ((size_t)part * U32d + u) * 512;
#pragma unroll
    for (int i = 0; i < 16; i += 2) {
        int q = (i & 3) + 8 * (i >> 2) + 4 * l5;     // even row of the pair
        opb[(q >> 1) * 32 + q32] = pkbf(O[i], O[i + 1]);
    }
    if (l5 == 0) Lsum[((size_t)part * U32d + u) * 32 + q32] = lsum;
}

// ------------------------------------------------ fused tail:
// split-K combine -> proj+bias+resid -> LN1 -> fc1+GELU -> fc2+bias+resid -> LN2
// 512 thr / 8 waves / 16 rows per block.
template<int LAST>
__global__ __launch_bounds__(512)
void tail_kernel(const unsigned* __restrict__ OPb, const float* __restrict__ Lsum,
                 const short* __restrict__ WT, const float* __restrict__ bias,
                 const float* __restrict__ resid,
                 const float* __restrict__ g1v, const float* __restrict__ be1v,
                 const short* __restrict__ W1T, const float* __restrict__ b1v,
                 const short* __restrict__ W2T, const float* __restrict__ b2v,
                 const float* __restrict__ g2v, const float* __restrict__ be2v,
                 float* __restrict__ outf, short* __restrict__ outb)
{
    __shared__ short Atile[16 * 264];
    __shared__ short A1[16 * 264];
    __shared__ short A2[16 * 264];
    __shared__ float red[8][16][2];
    int t = threadIdx.x;
    int rowBase = blockIdx.x * 16;

    // ---- combine: A[16][256] bf16 from OPb/Lsum
    {
        int r = t >> 5, seg = t & 31;
        int grow = rowBase + r;
        int bb = grow >> 11;
        int qt = (grow & (Nd - 1)) >> 5;
        int q = grow & 31;
        int h = seg >> 2;
        int dh0 = (seg & 3) * 8;
        int u = (bb * Hd + h) * 64 + qt;
        int sh = (q & 1) * 16;
        float o[8] = {0.f, 0.f, 0.f, 0.f, 0.f, 0.f, 0.f, 0.f};
        float L = 0.f;
#pragma unroll
        for (int p = 0; p < SPLITd; p++) {
            const unsigned* src = OPb + ((size_t)p * U32d + u) * 512 + (q >> 1) * 32 + dh0;
            uint4 w0 = *(const uint4*)src;
            uint4 w1 = *(const uint4*)(src + 4);
            o[0] += bf2f(w0.x >> sh); o[1] += bf2f(w0.y >> sh);
            o[2] += bf2f(w0.z >> sh); o[3] += bf2f(w0.w >> sh);
            o[4] += bf2f(w1.x >> sh); o[5] += bf2f(w1.y >> sh);
            o[6] += bf2f(w1.z >> sh); o[7] += bf2f(w1.w >> sh);
            L += Lsum[((size_t)p * U32d + u) * 32 + q];
        }
        float inv = 1.f / L;
        bf16x8 pk;
#pragma unroll
        for (int j = 0; j < 8; j++) pk[j] = f2bf(o[j] * inv);
        *(bf16x8*)&Atile[r * 264 + seg * 8] = pk;
    }
    __syncthreads();

    int w = t >> 6, l = t & 63, c = l & 15, g = l >> 4;
    const f32x4 zero = {0.f, 0.f, 0.f, 0.f};
    int col0 = w * 32 + c, col1 = col0 + 16;

    // ---- proj GEMM
    f32x4 acc0 = zero, acc1 = zero;
    {
        const short* bp0 = WT + (size_t)col0 * 256 + g * 8;
        const short* bp1 = WT + (size_t)col1 * 256 + g * 8;
#pragma unroll
        for (int kc = 0; kc < 256; kc += 32) {
            bf16x8 a = *(const bf16x8*)&Atile[c * 264 + g * 8 + kc];
            acc0 = mfma16(a, *(const bf16x8*)(bp0 + kc), acc0);
            acc1 = mfma16(a, *(const bf16x8*)(bp1 + kc), acc1);
        }
    }

    // ---- bias + residual, LN1 stats
    float vv[2][4], s_[4] = {0.f, 0.f, 0.f, 0.f}, sq_[4] = {0.f, 0.f, 0.f, 0.f};
    {
        float bi0 = bias[col0], bi1 = bias[col1];
#pragma unroll
        for (int r = 0; r < 4; r++) {
            int row = rowBase + 4 * g + r;
            float v0 = acc0[r] + bi0 + resid[(size_t)row * 256 + col0];
            float v1 = acc1[r] + bi1 + resid[(size_t)row * 256 + col1];
            vv[0][r] = v0; vv[1][r] = v1;
            s_[r] += v0 + v1; sq_[r] += v0 * v0 + v1 * v1;
        }
    }
#pragma unroll
    for (int off = 1; off <= 8; off <<= 1)
#pragma unroll
        for (int r = 0; r < 4; r++) {
            s_[r] += __shfl_xor(s_[r], off, 64);
            sq_[r] += __shfl_xor(sq_[r], off, 64);
        }
    if (c == 0)
#pragma unroll
        for (int r = 0; r < 4; r++) {
            red[w][4 * g + r][0] = s_[r];
            red[w][4 * g + r][1] = sq_[r];
        }
    __syncthreads();
    float ln1[2][4];
    {
        float mu[4], rs[4];
#pragma unroll
        for (int r = 0; r < 4; r++) {
            float S = 0.f, Q = 0.f;
#pragma unroll
            for (int ww = 0; ww < 8; ww++) { S += red[ww][4 * g + r][0]; Q += red[ww][4 * g + r][1]; }
            mu[r] = S * (1.f / 256.f);
            rs[r] = rsqrtf(Q * (1.f / 256.f) - mu[r] * mu[r] + 1e-6f);
        }
        float gv0 = g1v[col0], bv0 = be1v[col0], gv1 = g1v[col1], bv1 = be1v[col1];
#pragma unroll
        for (int r = 0; r < 4; r++) {
            float o0 = (vv[0][r] - mu[r]) * rs[r] * gv0 + bv0;
            float o1 = (vv[1][r] - mu[r]) * rs[r] * gv1 + bv1;
            ln1[0][r] = o0; ln1[1][r] = o1;
            A1[(4 * g + r) * 264 + col0] = f2bf(o0);
            A1[(4 * g + r) * 264 + col1] = f2bf(o1);
        }
    }
    __syncthreads();

    // ---- fc1 + GELU -> A2
    {
        f32x4 a0 = zero, a1 = zero;
        const short* bp0 = W1T + (size_t)col0 * 256 + g * 8;
        const short* bp1 = W1T + (size_t)col1 * 256 + g * 8;
#pragma unroll
        for (int kc = 0; kc < 256; kc += 32) {
            bf16x8 a = *(const bf16x8*)&A1[c * 264 + g * 8 + kc];
            a0 = mfma16(a, *(const bf16x8*)(bp0 + kc), a0);
            a1 = mfma16(a, *(const bf16x8*)(bp1 + kc), a1);
        }
        float bi0 = b1v[col0], bi1 = b1v[col1];
#pragma unroll
        for (int r = 0; r < 4; r++) {
            float v0 = a0[r] + bi0, v1 = a1[r] + bi1;
            v0 = 0.5f * v0 * (1.f + erff(v0 * 0.7071067811865476f));
            v1 = 0.5f * v1 * (1.f + erff(v1 * 0.7071067811865476f));
            A2[(4 * g + r) * 264 + col0] = f2bf(v0);
            A2[(4 * g + r) * 264 + col1] = f2bf(v1);
        }
    }
    __syncthreads();

    // ---- fc2 + bias + residual(LN1) + LN2
    acc0 = zero; acc1 = zero;
    {
        const short* bp0 = W2T + (size_t)col0 * 256 + g * 8;
        const short* bp1 = W2T + (size_t)col1 * 256 + g * 8;
#pragma unroll
        for (int kc = 0; kc < 256; kc += 32) {
            bf16x8 a = *(const bf16x8*)&A2[c * 264 + g * 8 + kc];
            acc0 = mfma16(a, *(const bf16x8*)(bp0 + kc), acc0);
            acc1 = mfma16(a, *(const bf16x8*)(bp1 + kc), acc1);
        }
    }
    {
        float bi0 = b2v[col0], bi1 = b2v[col1];
        float t0[4] = {0.f, 0.f, 0.f, 0.f}, t1[4] = {0.f, 0.f, 0.f, 0.f};
#pragma unroll
        for (int r = 0; r < 4; r++) {
            float v0 = acc0[r] + bi0 + ln1[0][r];
            float v1 = acc1[r] + bi1 + ln1[1][r];
            vv[0][r] = v0; vv[1][r] = v1;
            t0[r] = v0 + v1; t1[r] = v0 * v0 + v1 * v1;
        }
#pragma unroll
        for (int off = 1; off <= 8; off <<= 1)
#pragma unroll
            for (int r = 0; r < 4; r++) {
                t0[r] += __shfl_xor(t0[r], off, 64);
                t1[r] += __shfl_xor(t1[r], off, 64);
            }
        if (c == 0)
#pragma unroll
            for (int r = 0; r < 4; r++) {
                red[w][4 * g + r][0] = t0[r];
                red[w][4 * g + r][1] = t1[r];
            }
    }
    __syncthreads();
    {
        float mu[4], rs[4];
#pragma unroll
        for (int r = 0; r < 4; r++) {
            float S = 0.f, Q = 0.f;
#pragma unroll
            for (int ww = 0; ww < 8; ww++) { S += red[ww][4 * g + r][0]; Q += red[ww][4 * g + r][1]; }
            mu[r] = S * (1.f / 256.f);
            rs[r] = rsqrtf(Q * (1.f / 256.f) - mu[r] * mu[r] + 1e-6f);
        }
        float gv0 = g2v[col0], bv0 = be2v[col0], gv1 = g2v[col1], bv1 = be2v[col1];
#pragma unroll
        for (int r = 0; r < 4; r++) {
            int row = rowBase + 4 * g + r;
            float o0 = (vv[0][r] - mu[r]) * rs[r] * gv0 + bv0;
            float o1 = (vv[1][r] - mu[r]) * rs[r] * gv1 + bv1;
            outf[(size_t)row * 256 + col0] = o0;
            outf[(size_t)row * 256 + col1] = o1;
            if (!LAST) {
                outb[(size_t)row * 256 + col0] = f2bf(o0);
                outb[(size_t)row * 256 + col1] = f2bf(o1);
            }
        }
    }
}

// ------------------------------------------------ launch
extern "C" void kernel_launch(void* const* d_in, const int* in_sizes, int n_in,
                              void* d_out, int out_size, void* d_ws, size_t ws_size,
                              hipStream_t stream)
{
    const float* x_in   = (const float*)d_in[0];
    const float* qkv_w  = (const float*)d_in[1];
    const float* proj_w = (const float*)d_in[2];
    const float* proj_b = (const float*)d_in[3];
    const float* w1     = (const float*)d_in[4];
    const float* b1     = (const float*)d_in[5];
    const float* w2     = (const float*)d_in[6];
    const float* b2     = (const float*)d_in[7];
    const float* g1     = (const float*)d_in[8];
    const float* be1    = (const float*)d_in[9];
    const float* g2     = (const float*)d_in[10];
    const float* be2    = (const float*)d_in[11];
    float* outp = (float*)d_out;

    char* p = (char*)d_ws;
    float* xf    = (float*)p;    p += (size_t)Md * Cd * 4;
    short* xb    = (short*)p;    p += (size_t)Md * Cd * 2;
    short* Qh    = (short*)p;    p += (size_t)Md * Cd * 2;
    short* Kh    = (short*)p;    p += (size_t)Md * Cd * 2;
    short* Vtb   = (short*)p;    p += (size_t)Md * Cd * 2;
    unsigned* OPb = (unsigned*)p; p += (size_t)SPLITd * U32d * 512 * 4;
    float* Lsum  = (float*)p;    p += (size_t)SPLITd * U32d * 32 * 4;
    short* qkvT  = (short*)p;    p += (size_t)Ld * 768 * 256 * 2;
    short* projT = (short*)p;    p += (size_t)Ld * 256 * 256 * 2;
    short* w1T   = (short*)p;    p += (size_t)Ld * 256 * 256 * 2;
    short* w2T   = (short*)p;    p += (size_t)Ld * 256 * 256 * 2;

    const float QSCALE = 0.17677669529663687f * 1.4426950408889634f; // 1/sqrt(32)*log2e
    prep_kernel<<<1536 + Md * Cd / 256, 256, 0, stream>>>(
        x_in, qkv_w, proj_w, w1, w2, xf, xb, qkvT, projT, w1T, w2T, QSCALE);

    for (int l = 0; l < Ld; l++) {
        qkv_gemm_kernel<<<dim3(24, 32), 256, 0, stream>>>(
            xb, qkvT + (size_t)l * 768 * 256, Qh, Kh, Vtb);
        attn_part_kernel<<<512, 512, 0, stream>>>(Qh, Kh, Vtb, OPb, Lsum);
        if (l == Ld - 1)
            tail_kernel<1><<<Md / 16, 512, 0, stream>>>(
                OPb, Lsum, projT + (size_t)l * 65536, proj_b + l * 256, xf,
                g1 + l * 256, be1 + l * 256,
                w1T + (size_t)l * 65536, b1 + l * 256,
                w2T + (size_t)l * 65536, b2 + l * 256,
                g2 + l * 256, be2 + l * 256, outp, nullptr);
        else
            tail_kernel<0><<<Md / 16, 512, 0, stream>>>(
                OPb, Lsum, projT + (size_t)l * 65536, proj_b + l * 256, xf,
                g1 + l * 256, be1 + l * 256,
                w1T + (size_t)l * 65536, b1 + l * 256,
                w2T + (size_t)l * 65536, b2 + l * 256,
                g2 + l * 256, be2 + l * 256, xf, xb);
    }
}